// Round 1
// 465.769 us; speedup vs baseline: 1.4774x; 1.4774x over previous
//
#include <hip/hip_runtime.h>

#define H       4096
#define RANK    16
#define NROWS   16384      // BATCH * SEQ
#define RPB     2          // rows per block
#define TPB     256
#define TWO_OVER_PI 0.63661977236758134f

typedef float f32x4 __attribute__((ext_vector_type(4)));

// ---- prep: repack int32-stored int8 A/B into BIASED uint8 (v+128) ----
// A layout unchanged: word i = col (i>>2), ranks (i&3)*4..+3  -> int4 per column.
// B layout permuted so phase-2 thread t loads one int4 per rank:
//   out word o: c=o&3, t=(o>>2)&255, r=o>>10  <- in word r*1024 + c*256 + t
__global__ __launch_bounds__(256) void pack_ab(const int* __restrict__ A32,
                                               const int* __restrict__ B32,
                                               unsigned int* __restrict__ A8,
                                               unsigned int* __restrict__ B8) {
    int i = blockIdx.x * 256 + threadIdx.x;      // 0..16383
    int4 a = ((const int4*)A32)[i];
    A8[i] = ((unsigned)((a.x + 128) & 0xff))       | ((unsigned)((a.y + 128) & 0xff) << 8) |
            ((unsigned)((a.z + 128) & 0xff) << 16) | ((unsigned)((a.w + 128) & 0xff) << 24);

    int c = i & 3, tt = (i >> 2) & 255, r = i >> 10;
    int4 b = ((const int4*)B32)[r * 1024 + c * 256 + tt];
    B8[i] = ((unsigned)((b.x + 128) & 0xff))       | ((unsigned)((b.y + 128) & 0xff) << 8) |
            ((unsigned)((b.z + 128) & 0xff) << 16) | ((unsigned)((b.w + 128) & 0xff) << 24);
}

// ---- fused: h = x@A, out = x + 2*sin((h@B)*sB*2/pi) ----
// x lives in LDS (global_load_lds staging), never in long-lived VGPRs.
__global__ __launch_bounds__(TPB, 4) void pilora_fused(
    const float* __restrict__ x,
    const unsigned int* __restrict__ A8,    // [4096] int4-per-col, biased uint8
    const unsigned int* __restrict__ B8,    // permuted, biased uint8
    const float* __restrict__ sA,           // [16]
    const float* __restrict__ sB,           // [H]
    float* __restrict__ out)
{
    const int t    = threadIdx.x;
    const int lane = t & 63;
    const int wid  = t >> 6;
    const int row0 = blockIdx.x * RPB;

    __shared__ __attribute__((aligned(16))) float xs[RPB * H];   // 32 KB
    __shared__ float wsum[4][32];                                // per-wave partials
    __shared__ __attribute__((aligned(16))) float hsh[32];       // h[r][rr] at r*2+rr (scaled by sA)
    __shared__ float HsLds[RPB];                                 // 128 * sum_r h[rr][r]

    // ---- stage x rows (2 x 4096 f32 = 32 KB, contiguous) into LDS, 16B/lane ----
    const float* xrow = x + (size_t)row0 * H;
    #pragma unroll
    for (int i = 0; i < 8; ++i) {
        __builtin_amdgcn_global_load_lds(
            (const __attribute__((address_space(1))) unsigned int*)(xrow + i * 1024 + t * 4),
            (__attribute__((address_space(3)))       unsigned int*)(xs   + i * 1024 + t * 4),
            16, 0, 0);
    }
    __syncthreads();

    // ---- phase 1: per-thread partial h over this thread's 16 columns ----
    // w[j], j = rr*16 + r. biased: w = sum x*u ; corrected by -128*sum(x) at end.
    float w[32];
    #pragma unroll
    for (int j = 0; j < 32; ++j) w[j] = 0.0f;
    float sx0 = 0.0f, sx1 = 0.0f;

    const int4* A16 = (const int4*)A8;
    #pragma unroll
    for (int c = 0; c < 4; ++c) {
        f32x4 xv0 = *(const f32x4*)&xs[      c * 1024 + t * 4];
        f32x4 xv1 = *(const f32x4*)&xs[H +   c * 1024 + t * 4];
        #pragma unroll
        for (int e = 0; e < 4; ++e) {
            int4 q = A16[c * 1024 + t * 4 + e];
            float x0 = xv0[e], x1 = xv1[e];
            sx0 += x0; sx1 += x1;
            int qw[4] = {q.x, q.y, q.z, q.w};
            #pragma unroll
            for (int wi = 0; wi < 4; ++wi) {
                unsigned uw = (unsigned)qw[wi];
                #pragma unroll
                for (int b = 0; b < 4; ++b) {
                    float u = (float)((uw >> (8 * b)) & 0xffu);   // v_cvt_f32_ubyteN
                    w[     wi * 4 + b] += x0 * u;
                    w[16 + wi * 4 + b] += x1 * u;
                }
            }
        }
    }
    #pragma unroll
    for (int j = 0; j < 16; ++j) { w[j] -= 128.0f * sx0; w[16 + j] -= 128.0f * sx1; }

    // ---- in-wave butterfly reduction: 32 values over 64 lanes ----
    // after stage b, slot k holds value j = k*2^(b+1) + (lane & (2^(b+1)-1))
    #pragma unroll
    for (int b = 0; b < 5; ++b) {
        int q = (lane >> b) & 1;
        #pragma unroll
        for (int k = 0; k < (16 >> b); ++k) {
            float keep  = q ? w[2 * k + 1] : w[2 * k];
            float send  = q ? w[2 * k]     : w[2 * k + 1];
            float other = __shfl_xor(send, 1 << b, 64);
            w[k] = keep + other;
        }
    }
    w[0] += __shfl_xor(w[0], 32, 64);     // lane holds full-wave sum of j = lane&31

    if (lane < 32) wsum[wid][lane] = w[0];
    __syncthreads();

    // ---- cross-wave combine + scale; also Hs[rr] = 128 * sum_r h ----
    if (t < 32) {
        float v = wsum[0][t] + wsum[1][t] + wsum[2][t] + wsum[3][t];
        int r = t & 15, rr = t >> 4;
        float hv = v * sA[r];
        hsh[r * 2 + rr] = hv;
        float hs = hv;
        hs += __shfl_xor(hs, 1, 64);
        hs += __shfl_xor(hs, 2, 64);
        hs += __shfl_xor(hs, 4, 64);
        hs += __shfl_xor(hs, 8, 64);
        if (r == 0) HsLds[rr] = 128.0f * hs;
    }
    __syncthreads();

    // ---- phase 2: g[rr][j] = sum_r h[rr][r] * (u - 128) over thread's 16 cols ----
    float hf[32];
    #pragma unroll
    for (int k = 0; k < 8; ++k) *(f32x4*)&hf[k * 4] = *(const f32x4*)&hsh[k * 4];
    float hs0 = HsLds[0], hs1 = HsLds[1];

    float g0[16], g1[16];
    #pragma unroll
    for (int j = 0; j < 16; ++j) { g0[j] = -hs0; g1[j] = -hs1; }

    const int4* Bp = (const int4*)B8;
    #pragma unroll
    for (int r = 0; r < RANK; ++r) {
        float h0 = hf[r * 2 + 0], h1 = hf[r * 2 + 1];
        int4 bw = Bp[r * 256 + t];
        int bwa[4] = {bw.x, bw.y, bw.z, bw.w};
        #pragma unroll
        for (int wi = 0; wi < 4; ++wi) {
            unsigned uw = (unsigned)bwa[wi];
            #pragma unroll
            for (int b = 0; b < 4; ++b) {
                float u = (float)((uw >> (8 * b)) & 0xffu);
                g0[wi * 4 + b] += h0 * u;
                g1[wi * 4 + b] += h1 * u;
            }
        }
    }

    // ---- epilogue: out = x + 2*sin(g * sB * 2/pi); x re-read from LDS ----
    const float4* sB4 = (const float4*)sB;
    f32x4* o4 = (f32x4*)out;
    #pragma unroll
    for (int c = 0; c < 4; ++c) {
        float4 sb = sB4[c * 256 + t];
        float k0 = sb.x * TWO_OVER_PI;
        float k1 = sb.y * TWO_OVER_PI;
        float k2 = sb.z * TWO_OVER_PI;
        float k3 = sb.w * TWO_OVER_PI;
        f32x4 xv0 = *(const f32x4*)&xs[    c * 1024 + t * 4];
        f32x4 xv1 = *(const f32x4*)&xs[H + c * 1024 + t * 4];
        f32x4 o0, o1;
        o0[0] = xv0[0] + 2.0f * __sinf(g0[c * 4 + 0] * k0);
        o0[1] = xv0[1] + 2.0f * __sinf(g0[c * 4 + 1] * k1);
        o0[2] = xv0[2] + 2.0f * __sinf(g0[c * 4 + 2] * k2);
        o0[3] = xv0[3] + 2.0f * __sinf(g0[c * 4 + 3] * k3);
        o1[0] = xv1[0] + 2.0f * __sinf(g1[c * 4 + 0] * k0);
        o1[1] = xv1[1] + 2.0f * __sinf(g1[c * 4 + 1] * k1);
        o1[2] = xv1[2] + 2.0f * __sinf(g1[c * 4 + 2] * k2);
        o1[3] = xv1[3] + 2.0f * __sinf(g1[c * 4 + 3] * k3);
        __builtin_nontemporal_store(o0, &o4[(size_t)(row0 + 0) * 1024 + c * 256 + t]);
        __builtin_nontemporal_store(o1, &o4[(size_t)(row0 + 1) * 1024 + c * 256 + t]);
    }
}

extern "C" void kernel_launch(void* const* d_in, const int* in_sizes, int n_in,
                              void* d_out, int out_size, void* d_ws, size_t ws_size,
                              hipStream_t stream) {
    const float* x   = (const float*)d_in[0];
    const int*   A32 = (const int*)d_in[1];
    const int*   B32 = (const int*)d_in[2];
    const float* sA  = (const float*)d_in[3];
    const float* sB  = (const float*)d_in[4];
    float*       out = (float*)d_out;

    unsigned int* A8 = (unsigned int*)d_ws;               // 64 KB
    unsigned int* B8 = A8 + (H * RANK / 4);               // 64 KB

    pack_ab<<<(H * RANK / 4) / 256, 256, 0, stream>>>(A32, B32, A8, B8);
    pilora_fused<<<NROWS / RPB, TPB, 0, stream>>>(
        x, A8, B8, sA, sB, out);
}